// Round 1
// baseline (522.446 us; speedup 1.0000x reference)
//
#include <hip/hip_runtime.h>
#include <stdint.h>

#define SEQ   2048
#define HID   2048
#define NH    16
#define HD    128
#define BATCH 2

typedef unsigned short u16;
typedef __attribute__((ext_vector_type(8))) __bf16 bf16x8;
typedef __attribute__((ext_vector_type(4))) float  f32x4;

__device__ __forceinline__ u16 f2bf(float f) {
  union { float f; unsigned int u; } c; c.f = f;
  unsigned int u = c.u;
  return (u16)((u + 0x7fffu + ((u >> 16) & 1u)) >> 16);   // RNE
}
__device__ __forceinline__ float bf2f(u16 h) {
  union { unsigned int u; float f; } c; c.u = ((unsigned int)h) << 16;
  return c.f;
}

// async global->LDS, 16B per lane. LDS dest is wave-uniform base + lane*16.
__device__ __forceinline__ void async_ld16(const void* g, void* s) {
  using gptr_t = const __attribute__((address_space(1))) char*;
  using sptr_t = __attribute__((address_space(3))) char*;
  __builtin_amdgcn_global_load_lds((gptr_t)(uintptr_t)g, (sptr_t)(uintptr_t)s, 16, 0, 0);
}

// ---------------------------------------------------------------- cast fp32->bf16
__global__ void __launch_bounds__(256) cast_kernel(const float* __restrict__ in,
                                                   u16* __restrict__ out, int n4) {
  int i = blockIdx.x * 256 + threadIdx.x;
  if (i >= n4) return;
  const float4 v = ((const float4*)in)[i];
  union { u16 us[4]; uint2 u2; } o;
  o.us[0] = f2bf(v.x); o.us[1] = f2bf(v.y); o.us[2] = f2bf(v.z); o.us[3] = f2bf(v.w);
  ((uint2*)out)[i] = o.u2;
}

// ---------------------------------------------------------------- GEMM  C[m,n] = sum_k A[m,k]*W[n,k]
// m97 structure: 128x128 tile, BK=32, 4 waves (each a 64x64 quadrant, 4x4 MFMA tiles),
// async global_load_lds staging, ds_read_b128 fragments.
// MODE 0: bf16 out in [B,NH,S,HD] layout, blockIdx.z selects Wq/Wk/Wv -> Q/K/V.
// MODE 1: fp32 out row-major [M,HID].
template <int MODE>
__global__ void __launch_bounds__(256) gemm_bt_kernel(
    const u16* __restrict__ A,
    const u16* __restrict__ B0, const u16* __restrict__ B1, const u16* __restrict__ B2,
    void* __restrict__ O0, void* __restrict__ O1, void* __restrict__ O2) {
  const u16* Bw; void* Optr;
  if (MODE == 0) {
    const int z = blockIdx.z;
    Bw   = (z == 0) ? B0 : (z == 1) ? B1 : B2;
    Optr = (z == 0) ? O0 : (z == 1) ? O1 : O2;
  } else { Bw = B0; Optr = O0; }

  constexpr int Kd = HID;
  __shared__ u16 sA[128 * 32];
  __shared__ u16 sB[128 * 32];
  const int tid = threadIdx.x;
  const int w = tid >> 6, lane = tid & 63;
  const int wr = w >> 1, wc = w & 1;
  const int m0 = blockIdx.y * 128, n0 = blockIdx.x * 128;
  const int fr = lane & 15, fq = lane >> 4;
  const int srow = lane >> 2;           // 0..15 (row within 16-row wave chunk)
  const int scol = (lane & 3) * 16;     // byte offset within 64B row

  f32x4 acc[4][4] = {};
  const char* Ab = (const char*)A;
  const char* Bb = (const char*)Bw;
  char* sAc = (char*)sA;
  char* sBc = (char*)sB;

  for (int kt = 0; kt < Kd / 32; ++kt) {
    const int k0 = kt * 32;
#pragma unroll
    for (int j = 0; j < 2; ++j) {
      const int row = j * 64 + w * 16 + srow;
      async_ld16(Ab + ((size_t)(m0 + row) * Kd + k0) * 2 + scol, sAc + j * 4096 + w * 1024);
      async_ld16(Bb + ((size_t)(n0 + row) * Kd + k0) * 2 + scol, sBc + j * 4096 + w * 1024);
    }
    __syncthreads();   // compiler drains vmcnt(0) before barrier
    bf16x8 af[4], bfr[4];
#pragma unroll
    for (int i = 0; i < 4; ++i)
      af[i] = *(const bf16x8*)(sAc + ((wr * 64 + i * 16 + fr) * 32 + fq * 8) * 2);
#pragma unroll
    for (int j = 0; j < 4; ++j)
      bfr[j] = *(const bf16x8*)(sBc + ((wc * 64 + j * 16 + fr) * 32 + fq * 8) * 2);
#pragma unroll
    for (int i = 0; i < 4; ++i)
#pragma unroll
      for (int j = 0; j < 4; ++j)
        acc[i][j] = __builtin_amdgcn_mfma_f32_16x16x32_bf16(af[i], bfr[j], acc[i][j], 0, 0, 0);
    __syncthreads();
  }

  // epilogue: C/D layout col=lane&15, row=fq*4+reg
#pragma unroll
  for (int i = 0; i < 4; ++i) {
#pragma unroll
    for (int j = 0; j < 4; ++j) {
#pragma unroll
      for (int r = 0; r < 4; ++r) {
        const int m = m0 + wr * 64 + i * 16 + fq * 4 + r;
        const int n = n0 + wc * 64 + j * 16 + fr;
        const float v = acc[i][j][r];
        if (MODE == 0) {
          const int b = m >> 11, s = m & (SEQ - 1);
          const int h = n >> 7,  d = n & (HD - 1);
          ((u16*)Optr)[(((size_t)(b * NH + h) * SEQ + s) << 7) + d] = f2bf(v);
        } else {
          ((float*)Optr)[(size_t)m * HID + n] = v;
        }
      }
    }
  }
}

// ---------------------------------------------------------------- RoPE (in place on Q,K: [B,NH,S,HD] bf16)
__global__ void __launch_bounds__(256) rope_kernel(u16* __restrict__ Q, u16* __restrict__ K) {
  const int idx = blockIdx.x * 256 + threadIdx.x;   // over B*NH*S*64
  const int i  = idx & 63;
  const int s  = (idx >> 6) & (SEQ - 1);
  const int bh = idx >> 17;
  const size_t base = ((size_t)(bh * SEQ + s) << 7) + i;
  // inv_freq = 10000^(-2i/128) = 2^(-i * log2(10000)/64)
  const float inv = exp2f(-(float)i * 0.2076205059304601f);
  const float ang = (float)s * inv;
  const float c = cosf(ang), sn = sinf(ang);
  const float q0 = bf2f(Q[base]), q1 = bf2f(Q[base + 64]);
  Q[base]      = f2bf(q0 * c - q1 * sn);
  Q[base + 64] = f2bf(q1 * c + q0 * sn);
  const float k0 = bf2f(K[base]), k1 = bf2f(K[base + 64]);
  K[base]      = f2bf(k0 * c - k1 * sn);
  K[base + 64] = f2bf(k1 * c + k0 * sn);
}

// ---------------------------------------------------------------- V [B,NH,S,HD] -> Vt [B,NH,HD,S]
__global__ void __launch_bounds__(256) transpose_v_kernel(const u16* __restrict__ V,
                                                          u16* __restrict__ Vt) {
  __shared__ u16 tile[64][72];   // +8 pad
  const int s0 = blockIdx.x * 64, d0 = blockIdx.y * 64, bh = blockIdx.z;
  const int t = threadIdx.x;
#pragma unroll
  for (int pp = 0; pp < 2; ++pp) {
    const int id = pp * 256 + t;
    const int r = id >> 3, ch = (id & 7) * 8;
    *(uint4*)&tile[r][ch] = *(const uint4*)(V + ((size_t)(bh * SEQ + s0 + r) << 7) + d0 + ch);
  }
  __syncthreads();
#pragma unroll
  for (int pp = 0; pp < 2; ++pp) {
    const int id = pp * 256 + t;
    const int rd = id >> 3, ch = (id & 7) * 8;
    union { u16 us[8]; uint4 v4; } u;
#pragma unroll
    for (int i = 0; i < 8; ++i) u.us[i] = tile[ch + i][rd];
    *(uint4*)(Vt + ((size_t)(bh * HD + d0 + rd) << 11) + s0 + ch) = u.v4;
  }
}

// ---------------------------------------------------------------- flash attention
// grid (S/64 q-tiles, B*NH). block 256 = 4 waves; wave owns 16 q-rows.
// K-tile 64, online softmax, P via per-wave LDS (C-layout -> A-operand layout).
__global__ void __launch_bounds__(256) attn_kernel(const u16* __restrict__ Qg,
                                                   const u16* __restrict__ Kg,
                                                   const u16* __restrict__ Vtg,
                                                   u16* __restrict__ Ctx) {
  constexpr int QP = 136;  // 128+8 pad (bf16): breaks 16-way bank conflicts, keeps 16B align
  constexpr int VP = 72;   // 64+8 pad
  __shared__ u16 sQ[64 * QP];
  __shared__ u16 sK[64 * QP];
  __shared__ u16 sV[128 * VP];
  __shared__ u16 sP[4 * 16 * VP];

  const int qt = blockIdx.x, bh = blockIdx.y;
  const int b = bh >> 4, h = bh & (NH - 1);
  const int tid = threadIdx.x, w = tid >> 6, lane = tid & 63;
  const int fr = lane & 15, fq = lane >> 4;

  // stage Q tile [64][128]
#pragma unroll
  for (int pp = 0; pp < 4; ++pp) {
    const int row = pp * 16 + (tid >> 4);
    const int ch = (tid & 15) * 8;
    const uint4 v = *(const uint4*)(Qg + ((size_t)(bh * SEQ + qt * 64 + row) << 7) + ch);
    *(uint4*)&sQ[row * QP + ch] = v;
  }
  __syncthreads();
  bf16x8 qf[4];
#pragma unroll
  for (int ks = 0; ks < 4; ++ks)
    qf[ks] = *(const bf16x8*)&sQ[(w * 16 + fr) * QP + ks * 32 + fq * 8];

  f32x4 acco[8] = {};
  float mrow[4] = {-1e30f, -1e30f, -1e30f, -1e30f};
  float lrow[4] = {};
  const float scale = 0.08838834764831845f;   // 1/sqrt(128)

  for (int kt = 0; kt < SEQ / 64; ++kt) {
    // stage K tile [64][128] and Vt tile [128][64] (manual: padded LDS)
#pragma unroll
    for (int pp = 0; pp < 4; ++pp) {
      const int row = pp * 16 + (tid >> 4);
      const int ch = (tid & 15) * 8;
      const uint4 v = *(const uint4*)(Kg + ((size_t)(bh * SEQ + kt * 64 + row) << 7) + ch);
      *(uint4*)&sK[row * QP + ch] = v;
    }
#pragma unroll
    for (int pp = 0; pp < 4; ++pp) {
      const int row = pp * 32 + (tid >> 3);
      const int ch = (tid & 7) * 8;
      const uint4 v = *(const uint4*)(Vtg + ((size_t)(bh * HD + row) << 11) + kt * 64 + ch);
      *(uint4*)&sV[row * VP + ch] = v;
    }
    __syncthreads();

    // S = Q K^T  (wave's 16 q-rows x 64 keys)
    f32x4 accs[4] = {};
#pragma unroll
    for (int nt = 0; nt < 4; ++nt) {
#pragma unroll
      for (int ks = 0; ks < 4; ++ks) {
        const bf16x8 kf = *(const bf16x8*)&sK[(nt * 16 + fr) * QP + ks * 32 + fq * 8];
        accs[nt] = __builtin_amdgcn_mfma_f32_16x16x32_bf16(qf[ks], kf, accs[nt], 0, 0, 0);
      }
    }

    // online softmax. lane's rows: fq*4+r ; row spread over 16 lanes (fr) -> shfl_xor <16
    float pexp[4][4];
    float alpha[4];
#pragma unroll
    for (int r = 0; r < 4; ++r) {
      float mx = fmaxf(fmaxf(accs[0][r], accs[1][r]), fmaxf(accs[2][r], accs[3][r])) * scale;
#pragma unroll
      for (int d = 1; d < 16; d <<= 1) mx = fmaxf(mx, __shfl_xor(mx, d));
      const float mnew = fmaxf(mrow[r], mx);
      alpha[r] = __expf(mrow[r] - mnew);
      float rs = 0.f;
#pragma unroll
      for (int nt = 0; nt < 4; ++nt) {
        pexp[nt][r] = __expf(accs[nt][r] * scale - mnew);
        rs += pexp[nt][r];
      }
#pragma unroll
      for (int d = 1; d < 16; d <<= 1) rs += __shfl_xor(rs, d);
      lrow[r] = lrow[r] * alpha[r] + rs;
      mrow[r] = mnew;
    }
#pragma unroll
    for (int nt = 0; nt < 8; ++nt)
#pragma unroll
      for (int r = 0; r < 4; ++r) acco[nt][r] *= alpha[r];

    // P: C-layout regs -> per-wave LDS (A-operand layout for PV). Same-wave RAW: no barrier.
#pragma unroll
    for (int nt = 0; nt < 4; ++nt)
#pragma unroll
      for (int r = 0; r < 4; ++r)
        sP[(w * 16 + fq * 4 + r) * VP + nt * 16 + fr] = f2bf(pexp[nt][r]);

    // O += P V
    bf16x8 pf[2];
#pragma unroll
    for (int ks = 0; ks < 2; ++ks)
      pf[ks] = *(const bf16x8*)&sP[(w * 16 + fr) * VP + ks * 32 + fq * 8];
#pragma unroll
    for (int nt = 0; nt < 8; ++nt) {
#pragma unroll
      for (int ks = 0; ks < 2; ++ks) {
        const bf16x8 vf = *(const bf16x8*)&sV[(nt * 16 + fr) * VP + ks * 32 + fq * 8];
        acco[nt] = __builtin_amdgcn_mfma_f32_16x16x32_bf16(pf[ks], vf, acco[nt], 0, 0, 0);
      }
    }
    __syncthreads();   // protect sK/sV before next stage
  }

  // epilogue: Ctx[b*S+s][h*128+d] bf16
  float rcp[4];
#pragma unroll
  for (int r = 0; r < 4; ++r) rcp[r] = 1.f / lrow[r];
#pragma unroll
  for (int nt = 0; nt < 8; ++nt) {
#pragma unroll
    for (int r = 0; r < 4; ++r) {
      const int m = b * SEQ + qt * 64 + w * 16 + fq * 4 + r;
      const int n = h * HD + nt * 16 + fr;
      Ctx[(size_t)m * HID + n] = f2bf(acco[nt][r] * rcp[r]);
    }
  }
}

// ---------------------------------------------------------------- launcher
extern "C" void kernel_launch(void* const* d_in, const int* in_sizes, int n_in,
                              void* d_out, int out_size, void* d_ws, size_t ws_size,
                              hipStream_t stream) {
  (void)in_sizes; (void)n_in; (void)out_size; (void)ws_size;
  const float* X  = (const float*)d_in[0];
  const float* Wq = (const float*)d_in[1];
  const float* Wk = (const float*)d_in[2];
  const float* Wv = (const float*)d_in[3];
  const float* Wo = (const float*)d_in[4];
  float* out = (float*)d_out;
  char* ws = (char*)d_ws;
  const size_t MB = 1024 * 1024;
  u16* Xb  = (u16*)(ws + 0 * MB);    // 16 MB
  u16* Wqb = (u16*)(ws + 16 * MB);   // 8 MB each
  u16* Wkb = (u16*)(ws + 24 * MB);
  u16* Wvb = (u16*)(ws + 32 * MB);
  u16* Wob = (u16*)(ws + 40 * MB);
  u16* Qb  = (u16*)(ws + 48 * MB);   // [B,NH,S,HD] bf16, 16 MB
  u16* Kb  = (u16*)(ws + 64 * MB);
  u16* Vb  = (u16*)(ws + 80 * MB);
  u16* Vtb = (u16*)(ws + 96 * MB);   // [B,NH,HD,S]
  u16* Ctx = Vb;                     // V dead after transpose; reuse for attention output

  cast_kernel<<<8192, 256, 0, stream>>>(X,  Xb,  (BATCH * SEQ * HID) / 4);
  cast_kernel<<<4096, 256, 0, stream>>>(Wq, Wqb, (HID * HID) / 4);
  cast_kernel<<<4096, 256, 0, stream>>>(Wk, Wkb, (HID * HID) / 4);
  cast_kernel<<<4096, 256, 0, stream>>>(Wv, Wvb, (HID * HID) / 4);
  cast_kernel<<<4096, 256, 0, stream>>>(Wo, Wob, (HID * HID) / 4);

  gemm_bt_kernel<0><<<dim3(HID / 128, (BATCH * SEQ) / 128, 3), 256, 0, stream>>>(
      Xb, Wqb, Wkb, Wvb, Qb, Kb, Vb);
  rope_kernel<<<(BATCH * NH * SEQ * 64) / 256, 256, 0, stream>>>(Qb, Kb);
  transpose_v_kernel<<<dim3(SEQ / 64, HD / 64, BATCH * NH), 256, 0, stream>>>(Vb, Vtb);
  attn_kernel<<<dim3(SEQ / 64, BATCH * NH), 256, 0, stream>>>(Qb, Kb, Vtb, Ctx);
  gemm_bt_kernel<1><<<dim3(HID / 128, (BATCH * SEQ) / 128, 1), 256, 0, stream>>>(
      Ctx, Wob, nullptr, nullptr, out, nullptr, nullptr);
}

// Round 2
// 443.016 us; speedup vs baseline: 1.1793x; 1.1793x over previous
//
#include <hip/hip_runtime.h>
#include <stdint.h>

#define SEQ   2048
#define HID   2048
#define NH    16
#define HD    128
#define BATCH 2

typedef unsigned short u16;
typedef __attribute__((ext_vector_type(8))) __bf16 bf16x8;
typedef __attribute__((ext_vector_type(4))) __bf16 bf16x4;
typedef __attribute__((ext_vector_type(4))) float  f32x4;

__device__ __forceinline__ u16 f2bf(float f) {
  union { float f; unsigned int u; } c; c.f = f;
  unsigned int u = c.u;
  return (u16)((u + 0x7fffu + ((u >> 16) & 1u)) >> 16);   // RNE
}

// async global->LDS, 16B per lane. LDS dest is wave-uniform base + lane*16.
__device__ __forceinline__ void async_ld16(const void* g, void* s) {
  using gptr_t = const __attribute__((address_space(1))) char*;
  using sptr_t = __attribute__((address_space(3))) char*;
  __builtin_amdgcn_global_load_lds((gptr_t)(uintptr_t)g, (sptr_t)(uintptr_t)s, 16, 0, 0);
}

// ---------------------------------------------------------------- fused fp32->bf16 casts (5 tensors)
__global__ void __launch_bounds__(256) cast5_kernel(
    const float* __restrict__ X,  const float* __restrict__ Wq,
    const float* __restrict__ Wk, const float* __restrict__ Wv,
    const float* __restrict__ Wo,
    u16* __restrict__ Xb, u16* __restrict__ Wqb, u16* __restrict__ Wkb,
    u16* __restrict__ Wvb, u16* __restrict__ Wob) {
  const int seg = blockIdx.y;
  const float* in = (seg == 0) ? X : (seg == 1) ? Wq : (seg == 2) ? Wk : (seg == 3) ? Wv : Wo;
  u16* out = (seg == 0) ? Xb : (seg == 1) ? Wqb : (seg == 2) ? Wkb : (seg == 3) ? Wvb : Wob;
  const int n4 = (seg == 0) ? (BATCH * SEQ * HID / 4) : (HID * HID / 4);
  const int i = blockIdx.x * 256 + threadIdx.x;
  if (i >= n4) return;
  const float4 v = ((const float4*)in)[i];
  union { u16 us[4]; uint2 u2; } o;
  o.us[0] = f2bf(v.x); o.us[1] = f2bf(v.y); o.us[2] = f2bf(v.z); o.us[3] = f2bf(v.w);
  ((uint2*)out)[i] = o.u2;
}

// ---------------------------------------------------------------- GEMM  C[m,n] = sum_k A[m,k]*W[n,k]
template <int MODE>
__global__ void __launch_bounds__(256) gemm_bt_kernel(
    const u16* __restrict__ A,
    const u16* __restrict__ B0, const u16* __restrict__ B1, const u16* __restrict__ B2,
    void* __restrict__ O0, void* __restrict__ O1, void* __restrict__ O2) {
  const u16* Bw; void* Optr;
  if (MODE == 0) {
    const int z = blockIdx.z;
    Bw   = (z == 0) ? B0 : (z == 1) ? B1 : B2;
    Optr = (z == 0) ? O0 : (z == 1) ? O1 : O2;
  } else { Bw = B0; Optr = O0; }

  constexpr int Kd = HID;
  __shared__ u16 sA[128 * 32];
  __shared__ u16 sB[128 * 32];
  const int tid = threadIdx.x;
  const int w = tid >> 6, lane = tid & 63;
  const int wr = w >> 1, wc = w & 1;
  const int m0 = blockIdx.y * 128, n0 = blockIdx.x * 128;
  const int fr = lane & 15, fq = lane >> 4;
  const int srow = lane >> 2;
  const int scol = (lane & 3) * 16;

  f32x4 acc[4][4] = {};
  const char* Ab = (const char*)A;
  const char* Bb = (const char*)Bw;
  char* sAc = (char*)sA;
  char* sBc = (char*)sB;

  for (int kt = 0; kt < Kd / 32; ++kt) {
    const int k0 = kt * 32;
#pragma unroll
    for (int j = 0; j < 2; ++j) {
      const int row = j * 64 + w * 16 + srow;
      async_ld16(Ab + ((size_t)(m0 + row) * Kd + k0) * 2 + scol, sAc + j * 4096 + w * 1024);
      async_ld16(Bb + ((size_t)(n0 + row) * Kd + k0) * 2 + scol, sBc + j * 4096 + w * 1024);
    }
    __syncthreads();
    bf16x8 af[4], bfr[4];
#pragma unroll
    for (int i = 0; i < 4; ++i)
      af[i] = *(const bf16x8*)(sAc + ((wr * 64 + i * 16 + fr) * 32 + fq * 8) * 2);
#pragma unroll
    for (int j = 0; j < 4; ++j)
      bfr[j] = *(const bf16x8*)(sBc + ((wc * 64 + j * 16 + fr) * 32 + fq * 8) * 2);
#pragma unroll
    for (int i = 0; i < 4; ++i)
#pragma unroll
      for (int j = 0; j < 4; ++j)
        acc[i][j] = __builtin_amdgcn_mfma_f32_16x16x32_bf16(af[i], bfr[j], acc[i][j], 0, 0, 0);
    __syncthreads();
  }

#pragma unroll
  for (int i = 0; i < 4; ++i) {
#pragma unroll
    for (int j = 0; j < 4; ++j) {
#pragma unroll
      for (int r = 0; r < 4; ++r) {
        const int m = m0 + wr * 64 + i * 16 + fq * 4 + r;
        const int n = n0 + wc * 64 + j * 16 + fr;
        const float v = acc[i][j][r];
        if (MODE == 0) {
          const int b = m >> 11, s = m & (SEQ - 1);
          const int h = n >> 7,  d = n & (HD - 1);
          ((u16*)Optr)[(((size_t)(b * NH + h) * SEQ + s) << 7) + d] = f2bf(v);
        } else {
          ((float*)Optr)[(size_t)m * HID + n] = v;
        }
      }
    }
  }
}

// ---------------------------------------------------------------- RoPE (in place on Q,K: [B,NH,S,HD] bf16)
__global__ void __launch_bounds__(256) rope_kernel(u16* __restrict__ Q, u16* __restrict__ K) {
  const int idx = blockIdx.x * 256 + threadIdx.x;
  const int i  = idx & 63;
  const int s  = (idx >> 6) & (SEQ - 1);
  const int bh = idx >> 17;
  const size_t base = ((size_t)(bh * SEQ + s) << 7) + i;
  const float inv = exp2f(-(float)i * 0.2076205059304601f);
  const float ang = (float)s * inv;
  const float c = cosf(ang), sn = sinf(ang);
  auto bf2f = [](u16 h) { union { unsigned int u; float f; } c; c.u = ((unsigned int)h) << 16; return c.f; };
  const float q0 = bf2f(Q[base]), q1 = bf2f(Q[base + 64]);
  Q[base]      = f2bf(q0 * c - q1 * sn);
  Q[base + 64] = f2bf(q1 * c + q0 * sn);
  const float k0 = bf2f(K[base]), k1 = bf2f(K[base + 64]);
  K[base]      = f2bf(k0 * c - k1 * sn);
  K[base + 64] = f2bf(k1 * c + k0 * sn);
}

// ---------------------------------------------------------------- V [B,NH,S,HD] -> Vt [B,NH,HD,S]
__global__ void __launch_bounds__(256) transpose_v_kernel(const u16* __restrict__ V,
                                                          u16* __restrict__ Vt) {
  __shared__ u16 tile[64][72];
  const int s0 = blockIdx.x * 64, d0 = blockIdx.y * 64, bh = blockIdx.z;
  const int t = threadIdx.x;
#pragma unroll
  for (int pp = 0; pp < 2; ++pp) {
    const int id = pp * 256 + t;
    const int r = id >> 3, ch = (id & 7) * 8;
    *(uint4*)&tile[r][ch] = *(const uint4*)(V + ((size_t)(bh * SEQ + s0 + r) << 7) + d0 + ch);
  }
  __syncthreads();
#pragma unroll
  for (int pp = 0; pp < 2; ++pp) {
    const int id = pp * 256 + t;
    const int rd = id >> 3, ch = (id & 7) * 8;
    union { u16 us[8]; uint4 v4; } u;
#pragma unroll
    for (int i = 0; i < 8; ++i) u.us[i] = tile[ch + i][rd];
    *(uint4*)(Vt + ((size_t)(bh * HD + d0 + rd) << 11) + s0 + ch) = u.v4;
  }
}

// ---------------------------------------------------------------- flash attention, S^T = K Q^T orientation
// block 256 = 4 waves; wave owns 16 q-rows. Per kt: 64 keys.
// LDS 48KB: sK[4 chunks][64 rows][32] | sV[2 chunks][128 rows][32] | sQ chunks (reused as sP).
__global__ void __launch_bounds__(256, 3) attn_kernel(const u16* __restrict__ Qg,
                                                      const u16* __restrict__ Kg,
                                                      const u16* __restrict__ Vtg,
                                                      u16* __restrict__ Ctx) {
  __shared__ __align__(16) char smem[49152];
  char* sK  = smem;            // 16 KB: c*4096 + row*64 + part*16
  char* sV  = smem + 16384;    // 16 KB: ks*8192 + d*64 + part*16
  char* sQP = smem + 32768;    // 16 KB: Q chunks; later sP per-wave (w*2304, pitch 144B)

  const int qt = blockIdx.x, bh = blockIdx.y;
  const int b = bh >> 4, h = bh & (NH - 1);
  const int tid = threadIdx.x, w = tid >> 6, lane = tid & 63;
  const int fr = lane & 15, fq = lane >> 4;
  const int lrow = lane >> 2, lpart = lane & 3;

  const u16* Kbase = Kg  + (size_t)bh * SEQ * HD;
  const u16* Vbase = Vtg + (size_t)bh * HD * SEQ;
  const u16* Qbase = Qg  + (size_t)bh * SEQ * HD;

  // stage Q (once): chunked like K
#pragma unroll
  for (int c = 0; c < 4; ++c)
    async_ld16(Qbase + (size_t)(qt * 64 + w * 16 + lrow) * HD + c * 32 + lpart * 8,
               sQP + c * 4096 + w * 1024);
  __syncthreads();
  bf16x8 qf[4];
#pragma unroll
  for (int c = 0; c < 4; ++c)
    qf[c] = *(const bf16x8*)(sQP + c * 4096 + (w * 16 + fr) * 64 + fq * 16);

  char* sPw = sQP + w * 2304;   // 16 rows x 144B

  f32x4 acco[8] = {};
  float m_run = -1e30f, l_run = 0.f;
  const float scale2 = (float)(1.4426950408889634 / 11.313708498984761);  // log2(e)/sqrt(128)

  for (int kt = 0; kt < SEQ / 64; ++kt) {
    __syncthreads();   // all waves done with previous sK/sV (and kt=0: qf reads drained)
#pragma unroll
    for (int c = 0; c < 4; ++c)
      async_ld16(Kbase + (size_t)(kt * 64 + w * 16 + lrow) * HD + c * 32 + lpart * 8,
                 sK + c * 4096 + w * 1024);
#pragma unroll
    for (int i = 0; i < 4; ++i) {
      const int o = w * 4 + i, ks = o >> 3, rg = o & 7;
      async_ld16(Vbase + (size_t)(rg * 16 + lrow) * SEQ + kt * 64 + ks * 32 + lpart * 8,
                 sV + ks * 8192 + rg * 1024);
    }
    __syncthreads();   // vmcnt drained by compiler before barrier

    // S^T = K Q^T : accs[nt] tile over keys nt*16.., C-layout: col=q=fr, row=k_local=fq*4+r
    f32x4 accs[4] = {};
#pragma unroll
    for (int nt = 0; nt < 4; ++nt)
#pragma unroll
      for (int c = 0; c < 4; ++c) {
        const bf16x8 kf = *(const bf16x8*)(sK + c * 4096 + (nt * 16 + fr) * 64 + fq * 16);
        accs[nt] = __builtin_amdgcn_mfma_f32_16x16x32_bf16(kf, qf[c], accs[nt], 0, 0, 0);
      }

    // online softmax (log2 space). Lane's 16 values all belong to q=fr.
#pragma unroll
    for (int nt = 0; nt < 4; ++nt) accs[nt] *= scale2;
    f32x4 m4 = __builtin_elementwise_max(__builtin_elementwise_max(accs[0], accs[1]),
                                         __builtin_elementwise_max(accs[2], accs[3]));
    float mx = fmaxf(fmaxf(m4[0], m4[1]), fmaxf(m4[2], m4[3]));
    mx = fmaxf(mx, __shfl_xor(mx, 16));
    mx = fmaxf(mx, __shfl_xor(mx, 32));
    const float mnew = fmaxf(m_run, mx);
    const float alpha = __builtin_amdgcn_exp2f(m_run - mnew);
    m_run = mnew;
#pragma unroll
    for (int nt = 0; nt < 4; ++nt)
#pragma unroll
      for (int r = 0; r < 4; ++r)
        accs[nt][r] = __builtin_amdgcn_exp2f(accs[nt][r] - mnew);
    f32x4 rs4 = (accs[0] + accs[1]) + (accs[2] + accs[3]);
    float rs = (rs4[0] + rs4[1]) + (rs4[2] + rs4[3]);
    rs += __shfl_xor(rs, 16);
    rs += __shfl_xor(rs, 32);
    l_run = l_run * alpha + rs;
#pragma unroll
    for (int nt = 0; nt < 8; ++nt) acco[nt] *= alpha;

    // P^T -> sP rows [q=fr][k], packed b64 writes (lane holds k = nt*16+fq*4+r for q=fr)
#pragma unroll
    for (int nt = 0; nt < 4; ++nt) {
      const bf16x4 pb = __builtin_convertvector(accs[nt], bf16x4);
      *(bf16x4*)(sPw + fr * 144 + nt * 32 + fq * 8) = pb;
    }

    // O^T += Vt * P^T  (same-wave sP RAW: lgkmcnt ordering, no barrier)
    bf16x8 pf[2];
#pragma unroll
    for (int ks = 0; ks < 2; ++ks)
      pf[ks] = *(const bf16x8*)(sPw + fr * 144 + ks * 64 + fq * 16);
#pragma unroll
    for (int nt = 0; nt < 8; ++nt)
#pragma unroll
      for (int ks = 0; ks < 2; ++ks) {
        const bf16x8 vf = *(const bf16x8*)(sV + ks * 8192 + (nt * 16 + fr) * 64 + fq * 16);
        acco[nt] = __builtin_amdgcn_mfma_f32_16x16x32_bf16(vf, pf[ks], acco[nt], 0, 0, 0);
      }
  }

  __syncthreads();   // release sK/sV for epilogue staging
  // O^T C-layout: col=q=fr, row=d=nt*16+fq*4+r. Normalize, LDS-transpose, coalesced store.
  const float rcp = 1.f / l_run;
  char* ep = smem + w * 8192;   // 16 rows(q) x 272B (136 u16 pitch)
#pragma unroll
  for (int nt = 0; nt < 8; ++nt) {
    const f32x4 sc = acco[nt] * rcp;
    const bf16x4 pb = __builtin_convertvector(sc, bf16x4);
    *(bf16x4*)(ep + fr * 272 + nt * 32 + fq * 8) = pb;
  }
#pragma unroll
  for (int p = 0; p < 4; ++p) {
    const int rl = p * 4 + fq;
    const uint4 v = *(const uint4*)(ep + rl * 272 + fr * 16);
    *(uint4*)(Ctx + (size_t)(b * SEQ + qt * 64 + w * 16 + rl) * HID + h * HD + fr * 8) = v;
  }
}

// ---------------------------------------------------------------- launcher
extern "C" void kernel_launch(void* const* d_in, const int* in_sizes, int n_in,
                              void* d_out, int out_size, void* d_ws, size_t ws_size,
                              hipStream_t stream) {
  (void)in_sizes; (void)n_in; (void)out_size; (void)ws_size;
  const float* X  = (const float*)d_in[0];
  const float* Wq = (const float*)d_in[1];
  const float* Wk = (const float*)d_in[2];
  const float* Wv = (const float*)d_in[3];
  const float* Wo = (const float*)d_in[4];
  float* out = (float*)d_out;
  char* ws = (char*)d_ws;
  const size_t MB = 1024 * 1024;
  u16* Xb  = (u16*)(ws + 0 * MB);
  u16* Wqb = (u16*)(ws + 16 * MB);
  u16* Wkb = (u16*)(ws + 24 * MB);
  u16* Wvb = (u16*)(ws + 32 * MB);
  u16* Wob = (u16*)(ws + 40 * MB);
  u16* Qb  = (u16*)(ws + 48 * MB);
  u16* Kb  = (u16*)(ws + 64 * MB);
  u16* Vb  = (u16*)(ws + 80 * MB);
  u16* Vtb = (u16*)(ws + 96 * MB);
  u16* Ctx = Vb;   // V dead after transpose

  cast5_kernel<<<dim3(8192, 5), 256, 0, stream>>>(X, Wq, Wk, Wv, Wo,
                                                  Xb, Wqb, Wkb, Wvb, Wob);
  gemm_bt_kernel<0><<<dim3(HID / 128, (BATCH * SEQ) / 128, 3), 256, 0, stream>>>(
      Xb, Wqb, Wkb, Wvb, Qb, Kb, Vb);
  rope_kernel<<<(BATCH * NH * SEQ * 64) / 256, 256, 0, stream>>>(Qb, Kb);
  transpose_v_kernel<<<dim3(SEQ / 64, HD / 64, BATCH * NH), 256, 0, stream>>>(Vb, Vtb);
  attn_kernel<<<dim3(SEQ / 64, BATCH * NH), 256, 0, stream>>>(Qb, Kb, Vtb, Ctx);
  gemm_bt_kernel<1><<<dim3(HID / 128, (BATCH * SEQ) / 128, 1), 256, 0, stream>>>(
      Ctx, Wob, nullptr, nullptr, out, nullptr, nullptr);
}

// Round 4
// 404.908 us; speedup vs baseline: 1.2903x; 1.0941x over previous
//
#include <hip/hip_runtime.h>
#include <stdint.h>

#define SEQ   2048
#define HID   2048
#define NH    16
#define HD    128
#define BATCH 2

typedef unsigned short u16;
typedef unsigned int   u32;
typedef __attribute__((ext_vector_type(8)))  __bf16 bf16x8;
typedef __attribute__((ext_vector_type(4)))  __bf16 bf16x4;
typedef __attribute__((ext_vector_type(4)))  float  f32x4;
typedef __attribute__((ext_vector_type(16))) float  f32x16;

__device__ __forceinline__ u16 f2bf(float f) {
  union { float f; unsigned int u; } c; c.f = f;
  unsigned int u = c.u;
  return (u16)((u + 0x7fffu + ((u >> 16) & 1u)) >> 16);   // RNE
}

// async global->LDS, 16B/lane. HW writes wave-uniform LDS base + lane*16.
__device__ __forceinline__ void async_ld16(const void* g, void* s) {
  using gptr_t = const __attribute__((address_space(1))) char*;
  using sptr_t = __attribute__((address_space(3))) char*;
  __builtin_amdgcn_global_load_lds((gptr_t)(uintptr_t)g, (sptr_t)(uintptr_t)s, 16, 0, 0);
}

// ISA: vdst.hi32lanes <- vsrc.lo32lanes ; vsrc.lo32lanes <- vdst.hi32lanes
// => a' = {lo: a@own, hi: b@partner}; b' = {lo: a@partner, hi: b@own}
#if __has_builtin(__builtin_amdgcn_permlane32_swap)
__device__ __forceinline__ void plswap(u32& a, u32& b) {
  typedef __attribute__((ext_vector_type(2))) unsigned int u32x2;
  u32x2 r = __builtin_amdgcn_permlane32_swap(a, b, false, false);
  a = r[0]; b = r[1];
}
#else
__device__ __forceinline__ void plswap(u32& a, u32& b) {
  const int hi = (threadIdx.x & 63) >> 5;
  u32 sa = (u32)__shfl_xor((int)a, 32);
  u32 sb = (u32)__shfl_xor((int)b, 32);
  u32 na = hi ? sb : a;
  u32 nb = hi ? b  : sa;
  a = na; b = nb;
}
#endif

// ---------------------------------------------------------------- fused fp32->bf16 casts
__global__ void __launch_bounds__(256) cast5_kernel(
    const float* __restrict__ X,  const float* __restrict__ Wq,
    const float* __restrict__ Wk, const float* __restrict__ Wv,
    const float* __restrict__ Wo,
    u16* __restrict__ Xb, u16* __restrict__ Wqb, u16* __restrict__ Wkb,
    u16* __restrict__ Wvb, u16* __restrict__ Wob) {
  const int seg = blockIdx.y;
  const float* in = (seg == 0) ? X : (seg == 1) ? Wq : (seg == 2) ? Wk : (seg == 3) ? Wv : Wo;
  u16* out = (seg == 0) ? Xb : (seg == 1) ? Wqb : (seg == 2) ? Wkb : (seg == 3) ? Wvb : Wob;
  const int n4 = (seg == 0) ? (BATCH * SEQ * HID / 4) : (HID * HID / 4);
  const int i = blockIdx.x * 256 + threadIdx.x;
  if (i >= n4) return;
  const float4 v = ((const float4*)in)[i];
  union { u16 us[4]; uint2 u2; } o;
  o.us[0] = f2bf(v.x); o.us[1] = f2bf(v.y); o.us[2] = f2bf(v.z); o.us[3] = f2bf(v.w);
  ((uint2*)out)[i] = o.u2;
}

// ---------------------------------------------------------------- GEMM C[m,n] = sum_k A[m,k]*W[n,k]
// BK=64, full 128B rows, XOR-swizzled 16B units (u_phys = u_log ^ (row&7)).
template <int MODE>
__global__ void __launch_bounds__(256) gemm_bt_kernel(
    const u16* __restrict__ A,
    const u16* __restrict__ B0, const u16* __restrict__ B1, const u16* __restrict__ B2,
    void* __restrict__ O0, void* __restrict__ O1, void* __restrict__ O2) {
  const u16* Bw; void* Optr;
  if (MODE == 0) {
    const int z = blockIdx.z;
    Bw   = (z == 0) ? B0 : (z == 1) ? B1 : B2;
    Optr = (z == 0) ? O0 : (z == 1) ? O1 : O2;
  } else { Bw = B0; Optr = O0; }

  constexpr int Kd = HID;
  __shared__ __align__(16) char sAc[128 * 128];   // 16 KB
  __shared__ __align__(16) char sBc[128 * 128];
  const int tid = threadIdx.x;
  const int w = tid >> 6, lane = tid & 63;
  const int wr = w >> 1, wc = w & 1;
  const int m0 = blockIdx.y * 128, n0 = blockIdx.x * 128;
  const int fr = lane & 15, fq = lane >> 4;
  const int srow = lane >> 3;          // 0..7 row within 8-row KB block
  const int sup  = lane & 7;           // physical 16B unit

  f32x4 acc[4][4] = {};
  const u16* Ab = A;
  const u16* Bb = Bw;

  for (int kt = 0; kt < Kd / 64; ++kt) {
    const int k0 = kt * 64;
#pragma unroll
    for (int b2 = 0; b2 < 4; ++b2) {
      const int row = w * 32 + b2 * 8 + srow;
      const int ul = sup ^ (row & 7);
      async_ld16(Ab + (size_t)(m0 + row) * Kd + k0 + ul * 8, sAc + w * 4096 + b2 * 1024);
      async_ld16(Bb + (size_t)(n0 + row) * Kd + k0 + ul * 8, sBc + w * 4096 + b2 * 1024);
    }
    __syncthreads();
    bf16x8 af[2][4], bfr[2][4];
#pragma unroll
    for (int kc = 0; kc < 2; ++kc) {
#pragma unroll
      for (int i = 0; i < 4; ++i) {
        const int m = wr * 64 + i * 16 + fr;
        af[kc][i] = *(const bf16x8*)(sAc + m * 128 + ((kc * 4 + fq) ^ (m & 7)) * 16);
        const int n = wc * 64 + i * 16 + fr;
        bfr[kc][i] = *(const bf16x8*)(sBc + n * 128 + ((kc * 4 + fq) ^ (n & 7)) * 16);
      }
    }
#pragma unroll
    for (int kc = 0; kc < 2; ++kc)
#pragma unroll
      for (int i = 0; i < 4; ++i)
#pragma unroll
        for (int j = 0; j < 4; ++j)
          acc[i][j] = __builtin_amdgcn_mfma_f32_16x16x32_bf16(af[kc][i], bfr[kc][j], acc[i][j], 0, 0, 0);
    __syncthreads();
  }

#pragma unroll
  for (int i = 0; i < 4; ++i) {
#pragma unroll
    for (int j = 0; j < 4; ++j) {
#pragma unroll
      for (int r = 0; r < 4; ++r) {
        const int m = m0 + wr * 64 + i * 16 + fq * 4 + r;
        const int n = n0 + wc * 64 + j * 16 + fr;
        const float v = acc[i][j][r];
        if (MODE == 0) {
          const int b = m >> 11, s = m & (SEQ - 1);
          const int h = n >> 7,  d = n & (HD - 1);
          ((u16*)Optr)[(((size_t)(b * NH + h) * SEQ + s) << 7) + d] = f2bf(v);
        } else {
          ((float*)Optr)[(size_t)m * HID + n] = v;
        }
      }
    }
  }
}

// ---------------------------------------------------------------- RoPE (in place)
__global__ void __launch_bounds__(256) rope_kernel(u16* __restrict__ Q, u16* __restrict__ K) {
  const int idx = blockIdx.x * 256 + threadIdx.x;
  const int i  = idx & 63;
  const int s  = (idx >> 6) & (SEQ - 1);
  const int bh = idx >> 17;
  const size_t base = ((size_t)(bh * SEQ + s) << 7) + i;
  const float inv = exp2f(-(float)i * 0.2076205059304601f);
  const float ang = (float)s * inv;
  const float c = cosf(ang), sn = sinf(ang);
  auto bf2f = [](u16 h) { union { unsigned int u; float f; } c; c.u = ((unsigned int)h) << 16; return c.f; };
  const float q0 = bf2f(Q[base]), q1 = bf2f(Q[base + 64]);
  Q[base]      = f2bf(q0 * c - q1 * sn);
  Q[base + 64] = f2bf(q1 * c + q0 * sn);
  const float k0 = bf2f(K[base]), k1 = bf2f(K[base + 64]);
  K[base]      = f2bf(k0 * c - k1 * sn);
  K[base + 64] = f2bf(k1 * c + k0 * sn);
}

// ---------------------------------------------------------------- V [B,NH,S,HD] -> Vt [B,NH,HD,S]
__global__ void __launch_bounds__(256) transpose_v_kernel(const u16* __restrict__ V,
                                                          u16* __restrict__ Vt) {
  __shared__ u16 tile[64][72];
  const int s0 = blockIdx.x * 64, d0 = blockIdx.y * 64, bh = blockIdx.z;
  const int t = threadIdx.x;
#pragma unroll
  for (int pp = 0; pp < 2; ++pp) {
    const int id = pp * 256 + t;
    const int r = id >> 3, ch = (id & 7) * 8;
    *(uint4*)&tile[r][ch] = *(const uint4*)(V + ((size_t)(bh * SEQ + s0 + r) << 7) + d0 + ch);
  }
  __syncthreads();
#pragma unroll
  for (int pp = 0; pp < 2; ++pp) {
    const int id = pp * 256 + t;
    const int rd = id >> 3, ch = (id & 7) * 8;
    union { u16 us[8]; uint4 v4; } u;
#pragma unroll
    for (int i = 0; i < 8; ++i) u.us[i] = tile[ch + i][rd];
    *(uint4*)(Vt + ((size_t)(bh * HD + d0 + rd) << 11) + s0 + ch) = u.v4;
  }
}

// ---------------------------------------------------------------- flash attention, 32x32x16 MFMA
// BlockQ=128 (4 waves x 32q), 64 keys/kt. S^T = K*Q^T; O^T = Vt*P^T.
// sK: 64 rows x 256B swizzled (^row&15). sV: 128 rows x 128B swizzled (^row&7).
// Q staged once through whole smem, frags cached in regs. P via permlane32_swap.
__global__ void __launch_bounds__(256, 2) attn_kernel(const u16* __restrict__ Qg,
                                                      const u16* __restrict__ Kg,
                                                      const u16* __restrict__ Vtg,
                                                      u16* __restrict__ Ctx) {
  __shared__ __align__(16) char smem[32768];
  char* sV = smem + 16384;

  const int qt = blockIdx.x, bh = blockIdx.y;
  const int b = bh >> 4, h = bh & (NH - 1);
  const int tid = threadIdx.x, w = tid >> 6, lane = tid & 63;
  const int ml = lane & 31, hi = lane >> 5;

  const u16* Kbase = Kg  + (size_t)bh * SEQ * HD;
  const u16* Vbase = Vtg + (size_t)bh * HD * SEQ;
  const u16* Qbase = Qg  + (size_t)bh * SEQ * HD;

  // ---- stage Q tile 128 x 128 (32 KB) across whole smem, swizzled
  {
    const int r4 = lane >> 4;          // row within 4-row KB block
    const int up = lane & 15;
#pragma unroll
    for (int blk = 0; blk < 8; ++blk) {
      const int row = w * 32 + blk * 4 + r4;
      const int ul = up ^ (row & 15);
      async_ld16(Qbase + (size_t)(qt * 128 + row) * HD + ul * 8, smem + w * 8192 + blk * 1024);
    }
  }
  __syncthreads();
  const int qrow = w * 32 + ml;
  bf16x8 qf[8];
#pragma unroll
  for (int kc = 0; kc < 8; ++kc)
    qf[kc] = *(const bf16x8*)(smem + qrow * 256 + (((kc * 2 + hi) ^ (qrow & 15)) * 16));

  f32x16 acco[4] = {};
  float m_run = -1e30f, l_run = 0.f;
  const float scale2 = (float)(1.4426950408889634 / 11.313708498984761);  // log2(e)/sqrt(128)

  for (int kt = 0; kt < SEQ / 64; ++kt) {
    __syncthreads();   // prior compute done with sK/sV (kt=0: qf reads drained)
    {
      const int r4 = lane >> 4, up16 = lane & 15;
#pragma unroll
      for (int blk = 0; blk < 4; ++blk) {          // FIX: was blk < 2 -> half of K stale
        const int row = w * 16 + blk * 4 + r4;
        const int ul = up16 ^ (row & 15);
        async_ld16(Kbase + (size_t)(kt * 64 + row) * HD + ul * 8, smem + w * 4096 + blk * 1024);
      }
      const int r8 = lane >> 3, up8 = lane & 7;
#pragma unroll
      for (int blk = 0; blk < 4; ++blk) {
        const int d = w * 32 + blk * 8 + r8;
        const int ul = up8 ^ (d & 7);
        async_ld16(Vbase + (size_t)d * SEQ + kt * 64 + ul * 8, sV + w * 4096 + blk * 1024);
      }
    }
    __syncthreads();

    // ---- S^T = K Q^T : 2 tiles of 32x32 (keys t*32.., q cols)
    f32x16 accs[2] = {};
#pragma unroll
    for (int t = 0; t < 2; ++t) {
      const int row = t * 32 + ml;
#pragma unroll
      for (int kc = 0; kc < 8; ++kc) {
        const bf16x8 kf = *(const bf16x8*)(smem + row * 256 + (((kc * 2 + hi) ^ (row & 15)) * 16));
        accs[t] = __builtin_amdgcn_mfma_f32_32x32x16_bf16(kf, qf[kc], accs[t], 0, 0, 0);
      }
    }

    // ---- online softmax (log2 domain). Lane's col q = ml; keys: t*32 + (r&3)+8*(r>>2)+4*hi
    accs[0] *= scale2;
    accs[1] *= scale2;
    const f32x16 mm = __builtin_elementwise_max(accs[0], accs[1]);
    float mx = mm[0];
#pragma unroll
    for (int i = 1; i < 16; ++i) mx = fmaxf(mx, mm[i]);
    mx = fmaxf(mx, __shfl_xor(mx, 32));
    const float mnew = fmaxf(m_run, mx);
    const float alpha = __builtin_amdgcn_exp2f(m_run - mnew);
    m_run = mnew;
    float rs = 0.f;
#pragma unroll
    for (int t = 0; t < 2; ++t)
#pragma unroll
      for (int i = 0; i < 16; ++i) {
        accs[t][i] = __builtin_amdgcn_exp2f(accs[t][i] - mnew);
        rs += accs[t][i];
      }
    rs += __shfl_xor(rs, 32);
    l_run = l_run * alpha + rs;
#pragma unroll
    for (int dt = 0; dt < 4; ++dt) acco[dt] *= alpha;

    // ---- P pack (bf16) + lane<->lane+32 swap -> B-operand frags, 4 k-chunks of 16 keys
    u32 pk[2][4][2];
#pragma unroll
    for (int t = 0; t < 2; ++t)
#pragma unroll
      for (int g = 0; g < 4; ++g) {
        const f32x4 gv = {accs[t][4 * g], accs[t][4 * g + 1], accs[t][4 * g + 2], accs[t][4 * g + 3]};
        union { bf16x4 v; u32 u[2]; } cv; cv.v = __builtin_convertvector(gv, bf16x4);
        pk[t][g][0] = cv.u[0]; pk[t][g][1] = cv.u[1];
      }
    bf16x8 pf[4];
#pragma unroll
    for (int kc = 0; kc < 4; ++kc) {
      const int t = kc >> 1, g0 = (kc & 1) * 2;
      u32 a0 = pk[t][g0][0], a1 = pk[t][g0][1];
      u32 b0 = pk[t][g0 + 1][0], b1 = pk[t][g0 + 1][1];
      plswap(a0, b0); plswap(a1, b1);
      union { u32 u[4]; bf16x8 v; } fu;
      fu.u[0] = a0; fu.u[1] = a1; fu.u[2] = b0; fu.u[3] = b1;
      pf[kc] = fu.v;
    }

    // ---- O^T += Vt * P^T : 4 d-tiles of 32x32
#pragma unroll
    for (int dt = 0; dt < 4; ++dt) {
      const int d = dt * 32 + ml;
#pragma unroll
      for (int kc = 0; kc < 4; ++kc) {
        const bf16x8 vf = *(const bf16x8*)(sV + d * 128 + (((kc * 2 + hi) ^ (d & 7)) * 16));
        acco[dt] = __builtin_amdgcn_mfma_f32_32x32x16_bf16(vf, pf[kc], acco[dt], 0, 0, 0);
      }
    }
  }

  // ---- epilogue: normalize, LDS transpose (per-wave 8KB), coalesced b128 stores
  __syncthreads();
  const float rcp = 1.f / l_run;
  char* ep = smem + w * 8192;
#pragma unroll
  for (int dt = 0; dt < 4; ++dt) {
#pragma unroll
    for (int g = 0; g < 4; ++g) {
      const f32x4 gv = {acco[dt][4 * g] * rcp, acco[dt][4 * g + 1] * rcp,
                        acco[dt][4 * g + 2] * rcp, acco[dt][4 * g + 3] * rcp};
      union { bf16x4 v; uint2 u2; } cv; cv.v = __builtin_convertvector(gv, bf16x4);
      const int ul = dt * 4 + g;
      *(uint2*)(ep + ml * 256 + ((ul ^ (ml & 15)) * 16) + hi * 8) = cv.u2;
    }
  }
  __syncthreads();  // per-wave region + same-wave RAW; barrier also orders ds ops cheaply
#pragma unroll
  for (int rr = 0; rr < 8; ++rr) {
    const int id = rr * 64 + lane;
    const int qv = id >> 4, ul = id & 15;
    const uint4 v = *(const uint4*)(ep + qv * 256 + ((ul ^ (qv & 15)) * 16));
    *(uint4*)(Ctx + (size_t)(b * SEQ + qt * 128 + w * 32 + qv) * HID + h * HD + ul * 8) = v;
  }
}

// ---------------------------------------------------------------- launcher
extern "C" void kernel_launch(void* const* d_in, const int* in_sizes, int n_in,
                              void* d_out, int out_size, void* d_ws, size_t ws_size,
                              hipStream_t stream) {
  (void)in_sizes; (void)n_in; (void)out_size; (void)ws_size;
  const float* X  = (const float*)d_in[0];
  const float* Wq = (const float*)d_in[1];
  const float* Wk = (const float*)d_in[2];
  const float* Wv = (const float*)d_in[3];
  const float* Wo = (const float*)d_in[4];
  float* out = (float*)d_out;
  char* ws = (char*)d_ws;
  const size_t MB = 1024 * 1024;
  u16* Xb  = (u16*)(ws + 0 * MB);
  u16* Wqb = (u16*)(ws + 16 * MB);
  u16* Wkb = (u16*)(ws + 24 * MB);
  u16* Wvb = (u16*)(ws + 32 * MB);
  u16* Wob = (u16*)(ws + 40 * MB);
  u16* Qb  = (u16*)(ws + 48 * MB);
  u16* Kb  = (u16*)(ws + 64 * MB);
  u16* Vb  = (u16*)(ws + 80 * MB);
  u16* Vtb = (u16*)(ws + 96 * MB);
  u16* Ctx = Vb;   // V dead after transpose

  cast5_kernel<<<dim3(8192, 5), 256, 0, stream>>>(X, Wq, Wk, Wv, Wo,
                                                  Xb, Wqb, Wkb, Wvb, Wob);
  gemm_bt_kernel<0><<<dim3(HID / 128, (BATCH * SEQ) / 128, 3), 256, 0, stream>>>(
      Xb, Wqb, Wkb, Wvb, Qb, Kb, Vb);
  rope_kernel<<<(BATCH * NH * SEQ * 64) / 256, 256, 0, stream>>>(Qb, Kb);
  transpose_v_kernel<<<dim3(SEQ / 64, HD / 64, BATCH * NH), 256, 0, stream>>>(Vb, Vtb);
  attn_kernel<<<dim3(SEQ / 128, BATCH * NH), 256, 0, stream>>>(Qb, Kb, Vtb, Ctx);
  gemm_bt_kernel<1><<<dim3(HID / 128, (BATCH * SEQ) / 128, 1), 256, 0, stream>>>(
      Ctx, Wob, nullptr, nullptr, out, nullptr, nullptr);
}

// Round 5
// 371.911 us; speedup vs baseline: 1.4048x; 1.0887x over previous
//
#include <hip/hip_runtime.h>
#include <stdint.h>

#define SEQ   2048
#define HID   2048
#define NH    16
#define HD    128
#define BATCH 2

typedef unsigned short u16;
typedef unsigned int   u32;
typedef __attribute__((ext_vector_type(8)))  __bf16 bf16x8;
typedef __attribute__((ext_vector_type(4)))  __bf16 bf16x4;
typedef __attribute__((ext_vector_type(4)))  float  f32x4;
typedef __attribute__((ext_vector_type(16))) float  f32x16;

__device__ __forceinline__ u16 f2bf(float f) {
  union { float f; unsigned int u; } c; c.f = f;
  unsigned int u = c.u;
  return (u16)((u + 0x7fffu + ((u >> 16) & 1u)) >> 16);   // RNE
}

// async global->LDS, 16B/lane. HW writes wave-uniform LDS base + lane*16.
__device__ __forceinline__ void async_ld16(const void* g, void* s) {
  using gptr_t = const __attribute__((address_space(1))) char*;
  using sptr_t = __attribute__((address_space(3))) char*;
  __builtin_amdgcn_global_load_lds((gptr_t)(uintptr_t)g, (sptr_t)(uintptr_t)s, 16, 0, 0);
}

#if __has_builtin(__builtin_amdgcn_permlane32_swap)
__device__ __forceinline__ void plswap(u32& a, u32& b) {
  typedef __attribute__((ext_vector_type(2))) unsigned int u32x2;
  u32x2 r = __builtin_amdgcn_permlane32_swap(a, b, false, false);
  a = r[0]; b = r[1];
}
#else
__device__ __forceinline__ void plswap(u32& a, u32& b) {
  const int hi = (threadIdx.x & 63) >> 5;
  u32 sa = (u32)__shfl_xor((int)a, 32);
  u32 sb = (u32)__shfl_xor((int)b, 32);
  u32 na = hi ? sb : a;
  u32 nb = hi ? b  : sa;
  a = na; b = nb;
}
#endif

// ---------------------------------------------------------------- fused casts + rope tables
__global__ void __launch_bounds__(256) cast5_kernel(
    const float* __restrict__ X,  const float* __restrict__ Wq,
    const float* __restrict__ Wk, const float* __restrict__ Wv,
    const float* __restrict__ Wo,
    u16* __restrict__ Xb, u16* __restrict__ Wqb, u16* __restrict__ Wkb,
    u16* __restrict__ Wvb, u16* __restrict__ Wob,
    float* __restrict__ cosT, float* __restrict__ sinT) {
  const int seg = blockIdx.y;
  const int idx = blockIdx.x * 256 + threadIdx.x;
  if (seg == 5) {
    // rope tables: cosT/sinT[s][i], s<2048, i<64; 4 i's per thread
    if (idx >= SEQ * 64 / 4) return;
    const int s = idx >> 4, i0 = (idx & 15) * 4;
    float4 c, sn;
    float* cp = &c.x; float* sp = &sn.x;
#pragma unroll
    for (int e = 0; e < 4; ++e) {
      const float inv = exp2f(-(float)(i0 + e) * 0.20762050593045702f);  // log2(1e4)/64
      const float ang = (float)s * inv;
      cp[e] = cosf(ang); sp[e] = sinf(ang);
    }
    ((float4*)cosT)[idx] = c;
    ((float4*)sinT)[idx] = sn;
    return;
  }
  const float* in = (seg == 0) ? X : (seg == 1) ? Wq : (seg == 2) ? Wk : (seg == 3) ? Wv : Wo;
  u16* out = (seg == 0) ? Xb : (seg == 1) ? Wqb : (seg == 2) ? Wkb : (seg == 3) ? Wvb : Wob;
  const int n4 = (seg == 0) ? (BATCH * SEQ * HID / 4) : (HID * HID / 4);
  if (idx >= n4) return;
  const float4 v = ((const float4*)in)[idx];
  union { u16 us[4]; uint2 u2; } o;
  o.us[0] = f2bf(v.x); o.us[1] = f2bf(v.y); o.us[2] = f2bf(v.z); o.us[3] = f2bf(v.w);
  ((uint2*)out)[idx] = o.u2;
}

// ---------------------------------------------------------------- GEMM C[m,n] = sum_k A[m,k]*W[n,k]
// BK=64, swizzled rows. MFMA operand-swapped => acc holds C^T: col=m (lane&15), row=n (fq*4+r).
// MODE 0: z=0/1 -> Q/K with fused RoPE, [B,NH,S,HD] bf16; z=2 -> V written transposed [B,NH,HD,S].
// MODE 1: fp32 row-major out, direct float4 stores.
template <int MODE>
__global__ void __launch_bounds__(256) gemm_bt_kernel(
    const u16* __restrict__ A,
    const u16* __restrict__ B0, const u16* __restrict__ B1, const u16* __restrict__ B2,
    void* __restrict__ O0, void* __restrict__ O1, void* __restrict__ O2,
    const float* __restrict__ cosT, const float* __restrict__ sinT) {
  const u16* Bw; void* Optr; int z = 0;
  if (MODE == 0) {
    z = blockIdx.z;
    Bw   = (z == 0) ? B0 : (z == 1) ? B1 : B2;
    Optr = (z == 0) ? O0 : (z == 1) ? O1 : O2;
  } else { Bw = B0; Optr = O0; }

  constexpr int Kd = HID;
  __shared__ __align__(16) char smem[32768];
  char* sAc = smem;
  char* sBc = smem + 16384;
  const int tid = threadIdx.x;
  const int w = tid >> 6, lane = tid & 63;
  const int wr = w >> 1, wc = w & 1;
  const int m0 = blockIdx.y * 128, n0 = blockIdx.x * 128;
  const int fr = lane & 15, fq = lane >> 4;
  const int srow = lane >> 3;          // 0..7 row within 8-row KB block
  const int sup  = lane & 7;           // physical 16B unit

  f32x4 acc[4][4] = {};
  const u16* Ab = A;
  const u16* Bb = Bw;

  for (int kt = 0; kt < Kd / 64; ++kt) {
    const int k0 = kt * 64;
#pragma unroll
    for (int b2 = 0; b2 < 4; ++b2) {
      const int row = w * 32 + b2 * 8 + srow;
      const int ul = sup ^ (row & 7);
      async_ld16(Ab + (size_t)(m0 + row) * Kd + k0 + ul * 8, sAc + w * 4096 + b2 * 1024);
      async_ld16(Bb + (size_t)(n0 + row) * Kd + k0 + ul * 8, sBc + w * 4096 + b2 * 1024);
    }
    __syncthreads();
    bf16x8 af[2][4], bfr[2][4];
#pragma unroll
    for (int kc = 0; kc < 2; ++kc) {
#pragma unroll
      for (int i = 0; i < 4; ++i) {
        const int m = wr * 64 + i * 16 + fr;
        af[kc][i] = *(const bf16x8*)(sAc + m * 128 + ((kc * 4 + fq) ^ (m & 7)) * 16);
        const int n = wc * 64 + i * 16 + fr;
        bfr[kc][i] = *(const bf16x8*)(sBc + n * 128 + ((kc * 4 + fq) ^ (n & 7)) * 16);
      }
    }
#pragma unroll
    for (int kc = 0; kc < 2; ++kc)
#pragma unroll
      for (int i = 0; i < 4; ++i)
#pragma unroll
        for (int j = 0; j < 4; ++j)   // operand swap: D = C^T (col=m, row=n)
          acc[i][j] = __builtin_amdgcn_mfma_f32_16x16x32_bf16(bfr[kc][j], af[kc][i], acc[i][j], 0, 0, 0);
    __syncthreads();
  }
  // (loop's trailing barrier: all frag reads drained; smem reusable)

  if (MODE == 1) {
#pragma unroll
    for (int i = 0; i < 4; ++i)
#pragma unroll
      for (int j = 0; j < 4; ++j) {
        const int m = m0 + wr * 64 + i * 16 + fr;
        const int n = n0 + wc * 64 + j * 16 + fq * 4;
        const float4 v = {acc[i][j][0], acc[i][j][1], acc[i][j][2], acc[i][j][3]};
        *(float4*)((float*)Optr + (size_t)m * HID + n) = v;
      }
    return;
  }

  const int h = n0 >> 7;   // one head per 128-col block
  u16* Og = (u16*)Optr;
  if (z < 2) {
    // ---- stage packed C [m][n] bf16, pitch 256B, 16B-unit swizzle ^(m&15)
#pragma unroll
    for (int i = 0; i < 4; ++i)
#pragma unroll
      for (int j = 0; j < 4; ++j) {
        const int m = wr * 64 + i * 16 + fr;
        const int nb = wc * 64 + j * 16 + fq * 4;
        union { bf16x4 v; uint2 u; } cv;
        cv.v = __builtin_convertvector(acc[i][j], bf16x4);
        *(uint2*)(smem + m * 256 + (((nb >> 3) ^ (m & 15)) * 16) + (nb & 7) * 2) = cv.u;
      }
    __syncthreads();
    // ---- rope + coalesced store
#pragma unroll
    for (int rr = 0; rr < 8; ++rr) {
      const int row = rr * 16 + (tid >> 4);
      const int nb = (tid & 15) * 8;
      const int i0 = nb & 63;
      const bf16x8 x  = *(const bf16x8*)(smem + row * 256 + (((nb >> 3) ^ (row & 15)) * 16));
      const bf16x8 xp = *(const bf16x8*)(smem + row * 256 + ((((nb ^ 64) >> 3) ^ (row & 15)) * 16));
      const int mg = m0 + row;
      const int s = mg & (SEQ - 1), b = mg >> 11;
      const float4 c0 = *(const float4*)(cosT + s * 64 + i0);
      const float4 c1 = *(const float4*)(cosT + s * 64 + i0 + 4);
      const float4 s0 = *(const float4*)(sinT + s * 64 + i0);
      const float4 s1 = *(const float4*)(sinT + s * 64 + i0 + 4);
      const float cs[8] = {c0.x, c0.y, c0.z, c0.w, c1.x, c1.y, c1.z, c1.w};
      const float sn[8] = {s0.x, s0.y, s0.z, s0.w, s1.x, s1.y, s1.z, s1.w};
      const float sgn = (nb < 64) ? -1.f : 1.f;
      union { bf16x8 v; uint4 u; } o;
#pragma unroll
      for (int e = 0; e < 8; ++e)
        o.v[e] = (__bf16)((float)x[e] * cs[e] + sgn * (float)xp[e] * sn[e]);
      *(uint4*)(Og + (((size_t)(b * NH + h) * SEQ + s) << 7) + nb) = o.u;
    }
  } else {
    // ---- V: stage C^T [n=d][m=s] scalar, then coalesced Vt stores
#pragma unroll
    for (int i = 0; i < 4; ++i)
#pragma unroll
      for (int j = 0; j < 4; ++j)
#pragma unroll
        for (int r = 0; r < 4; ++r) {
          const int m = wr * 64 + i * 16 + fr;
          const int n = wc * 64 + j * 16 + fq * 4 + r;
          *(u16*)(smem + n * 256 + (((m >> 3) ^ (n & 15)) * 16) + (m & 7) * 2) = f2bf(acc[i][j][r]);
        }
    __syncthreads();
#pragma unroll
    for (int rr = 0; rr < 8; ++rr) {
      const int d = rr * 16 + (tid >> 4);
      const int mb = (tid & 15) * 8;
      const uint4 v = *(const uint4*)(smem + d * 256 + (((mb >> 3) ^ (d & 15)) * 16));
      const int mg = m0 + mb;
      const int s = mg & (SEQ - 1), b = mg >> 11;
      *(uint4*)(Og + (((size_t)((b * NH + h) * HD + d)) << 11) + s) = v;
    }
  }
}

// ---------------------------------------------------------------- flash attention, 32x32x16 MFMA
// BlockQ=128 (4 waves x 32q), 64 keys/kt. S^T = K*Q^T; O^T = Vt*P^T.
__global__ void __launch_bounds__(256, 2) attn_kernel(const u16* __restrict__ Qg,
                                                      const u16* __restrict__ Kg,
                                                      const u16* __restrict__ Vtg,
                                                      u16* __restrict__ Ctx) {
  __shared__ __align__(16) char smem[32768];
  char* sV = smem + 16384;

  const int qt = blockIdx.x, bh = blockIdx.y;
  const int b = bh >> 4, h = bh & (NH - 1);
  const int tid = threadIdx.x, w = tid >> 6, lane = tid & 63;
  const int ml = lane & 31, hi = lane >> 5;

  const u16* Kbase = Kg  + (size_t)bh * SEQ * HD;
  const u16* Vbase = Vtg + (size_t)bh * HD * SEQ;
  const u16* Qbase = Qg  + (size_t)bh * SEQ * HD;

  // ---- stage Q tile 128 x 128 (32 KB) across whole smem, swizzled
  {
    const int r4 = lane >> 4;
    const int up = lane & 15;
#pragma unroll
    for (int blk = 0; blk < 8; ++blk) {
      const int row = w * 32 + blk * 4 + r4;
      const int ul = up ^ (row & 15);
      async_ld16(Qbase + (size_t)(qt * 128 + row) * HD + ul * 8, smem + w * 8192 + blk * 1024);
    }
  }
  __syncthreads();
  const int qrow = w * 32 + ml;
  bf16x8 qf[8];
#pragma unroll
  for (int kc = 0; kc < 8; ++kc)
    qf[kc] = *(const bf16x8*)(smem + qrow * 256 + (((kc * 2 + hi) ^ (qrow & 15)) * 16));

  f32x16 acco[4] = {};
  float m_run = -1e30f, l_run = 0.f;
  const float scale2 = (float)(1.4426950408889634 / 11.313708498984761);  // log2(e)/sqrt(128)

  for (int kt = 0; kt < SEQ / 64; ++kt) {
    __syncthreads();
    {
      const int r4 = lane >> 4, up16 = lane & 15;
#pragma unroll
      for (int blk = 0; blk < 4; ++blk) {
        const int row = w * 16 + blk * 4 + r4;
        const int ul = up16 ^ (row & 15);
        async_ld16(Kbase + (size_t)(kt * 64 + row) * HD + ul * 8, smem + w * 4096 + blk * 1024);
      }
      const int r8 = lane >> 3, up8 = lane & 7;
#pragma unroll
      for (int blk = 0; blk < 4; ++blk) {
        const int d = w * 32 + blk * 8 + r8;
        const int ul = up8 ^ (d & 7);
        async_ld16(Vbase + (size_t)d * SEQ + kt * 64 + ul * 8, sV + w * 4096 + blk * 1024);
      }
    }
    __syncthreads();

    f32x16 accs[2] = {};
#pragma unroll
    for (int t = 0; t < 2; ++t) {
      const int row = t * 32 + ml;
#pragma unroll
      for (int kc = 0; kc < 8; ++kc) {
        const bf16x8 kf = *(const bf16x8*)(smem + row * 256 + (((kc * 2 + hi) ^ (row & 15)) * 16));
        accs[t] = __builtin_amdgcn_mfma_f32_32x32x16_bf16(kf, qf[kc], accs[t], 0, 0, 0);
      }
    }

    accs[0] *= scale2;
    accs[1] *= scale2;
    const f32x16 mm = __builtin_elementwise_max(accs[0], accs[1]);
    float mx = mm[0];
#pragma unroll
    for (int i = 1; i < 16; ++i) mx = fmaxf(mx, mm[i]);
    mx = fmaxf(mx, __shfl_xor(mx, 32));
    const float mnew = fmaxf(m_run, mx);
    const float alpha = __builtin_amdgcn_exp2f(m_run - mnew);
    m_run = mnew;
    float rs = 0.f;
#pragma unroll
    for (int t = 0; t < 2; ++t)
#pragma unroll
      for (int i = 0; i < 16; ++i) {
        accs[t][i] = __builtin_amdgcn_exp2f(accs[t][i] - mnew);
        rs += accs[t][i];
      }
    rs += __shfl_xor(rs, 32);
    l_run = l_run * alpha + rs;
#pragma unroll
    for (int dt = 0; dt < 4; ++dt) acco[dt] *= alpha;

    u32 pk[2][4][2];
#pragma unroll
    for (int t = 0; t < 2; ++t)
#pragma unroll
      for (int g = 0; g < 4; ++g) {
        const f32x4 gv = {accs[t][4 * g], accs[t][4 * g + 1], accs[t][4 * g + 2], accs[t][4 * g + 3]};
        union { bf16x4 v; u32 u[2]; } cv; cv.v = __builtin_convertvector(gv, bf16x4);
        pk[t][g][0] = cv.u[0]; pk[t][g][1] = cv.u[1];
      }
    bf16x8 pf[4];
#pragma unroll
    for (int kc = 0; kc < 4; ++kc) {
      const int t = kc >> 1, g0 = (kc & 1) * 2;
      u32 a0 = pk[t][g0][0], a1 = pk[t][g0][1];
      u32 b0 = pk[t][g0 + 1][0], b1 = pk[t][g0 + 1][1];
      plswap(a0, b0); plswap(a1, b1);
      union { u32 u[4]; bf16x8 v; } fu;
      fu.u[0] = a0; fu.u[1] = a1; fu.u[2] = b0; fu.u[3] = b1;
      pf[kc] = fu.v;
    }

#pragma unroll
    for (int dt = 0; dt < 4; ++dt) {
      const int d = dt * 32 + ml;
#pragma unroll
      for (int kc = 0; kc < 4; ++kc) {
        const bf16x8 vf = *(const bf16x8*)(sV + d * 128 + (((kc * 2 + hi) ^ (d & 7)) * 16));
        acco[dt] = __builtin_amdgcn_mfma_f32_32x32x16_bf16(vf, pf[kc], acco[dt], 0, 0, 0);
      }
    }
  }

  __syncthreads();
  const float rcp = 1.f / l_run;
  char* ep = smem + w * 8192;
#pragma unroll
  for (int dt = 0; dt < 4; ++dt) {
#pragma unroll
    for (int g = 0; g < 4; ++g) {
      const f32x4 gv = {acco[dt][4 * g] * rcp, acco[dt][4 * g + 1] * rcp,
                        acco[dt][4 * g + 2] * rcp, acco[dt][4 * g + 3] * rcp};
      union { bf16x4 v; uint2 u2; } cv; cv.v = __builtin_convertvector(gv, bf16x4);
      const int ul = dt * 4 + g;
      *(uint2*)(ep + ml * 256 + ((ul ^ (ml & 15)) * 16) + hi * 8) = cv.u2;
    }
  }
  __syncthreads();
#pragma unroll
  for (int rr = 0; rr < 8; ++rr) {
    const int id = rr * 64 + lane;
    const int qv = id >> 4, ul = id & 15;
    const uint4 v = *(const uint4*)(ep + qv * 256 + ((ul ^ (qv & 15)) * 16));
    *(uint4*)(Ctx + (size_t)(b * SEQ + qt * 128 + w * 32 + qv) * HID + h * HD + ul * 8) = v;
  }
}

// ---------------------------------------------------------------- launcher
extern "C" void kernel_launch(void* const* d_in, const int* in_sizes, int n_in,
                              void* d_out, int out_size, void* d_ws, size_t ws_size,
                              hipStream_t stream) {
  (void)in_sizes; (void)n_in; (void)out_size; (void)ws_size;
  const float* X  = (const float*)d_in[0];
  const float* Wq = (const float*)d_in[1];
  const float* Wk = (const float*)d_in[2];
  const float* Wv = (const float*)d_in[3];
  const float* Wo = (const float*)d_in[4];
  float* out = (float*)d_out;
  char* ws = (char*)d_ws;
  const size_t MB = 1024 * 1024;
  u16* Xb  = (u16*)(ws + 0 * MB);
  u16* Wqb = (u16*)(ws + 16 * MB);
  u16* Wkb = (u16*)(ws + 24 * MB);
  u16* Wvb = (u16*)(ws + 32 * MB);
  u16* Wob = (u16*)(ws + 40 * MB);
  u16* Qb  = (u16*)(ws + 48 * MB);
  u16* Kb  = (u16*)(ws + 64 * MB);
  u16* Vtb = (u16*)(ws + 80 * MB);   // [B,NH,HD,S] — written directly by gemm<0> z=2
  // rope tables live in the Ctx region: read only by gemm<0>, dead before attn writes Ctx
  float* cosT = (float*)(ws + 96 * MB);
  float* sinT = cosT + SEQ * 64;
  u16* Ctx = (u16*)(ws + 96 * MB);

  cast5_kernel<<<dim3(8192, 6), 256, 0, stream>>>(X, Wq, Wk, Wv, Wo,
                                                  Xb, Wqb, Wkb, Wvb, Wob, cosT, sinT);
  gemm_bt_kernel<0><<<dim3(HID / 128, (BATCH * SEQ) / 128, 3), 256, 0, stream>>>(
      Xb, Wqb, Wkb, Wvb, Qb, Kb, Vtb, cosT, sinT);
  attn_kernel<<<dim3(SEQ / 128, BATCH * NH), 256, 0, stream>>>(Qb, Kb, Vtb, Ctx);
  gemm_bt_kernel<1><<<dim3(HID / 128, (BATCH * SEQ) / 128, 1), 256, 0, stream>>>(
      Ctx, Wob, nullptr, nullptr, out, nullptr, nullptr, nullptr, nullptr);
}